// Round 3
// baseline (389.397 us; speedup 1.0000x reference)
//
#include <hip/hip_runtime.h>
#include <hip/hip_bf16.h>

// Problem constants
#define IN_DIM 128
#define HID    64
#define NFW    8256     // IN*HID + HID
#define BATCH  256
#define K2     16512    // 2*NFW
#define BM     64       // rows per m-block
#define NMB    129      // 8256/64
#define KSPLIT 6
#define NT_PER 43       // k-tiles (of 64) per split; 6*43 = 258 total
#define GRID_M 774      // NMB * KSPLIT

typedef float f32x4 __attribute__((ext_vector_type(4)));
typedef short bf16x8 __attribute__((ext_vector_type(8)));

__device__ __forceinline__ unsigned int f2bf(float f) {
    union { float f; unsigned int u; } v; v.f = f;
    return (v.u + 0x7FFFu + ((v.u >> 16) & 1u)) >> 16;   // RNE f32->bf16 (bits)
}

// ---------------------------------------------------------------------------
// Kernel 0: W1 (16512x128 f32) -> W1T tiled bf16. Tile kt: [128 n][64 kl].
// ---------------------------------------------------------------------------
__global__ __launch_bounds__(256) void k_prep_w1t(const float* __restrict__ W1,
                                                  unsigned short* __restrict__ W1T) {
    __shared__ float tile[64][IN_DIM + 1];
    const int kt = blockIdx.x;               // 0..257
    const int t  = threadIdx.x;
    const float* src = W1 + (size_t)kt * 64 * IN_DIM;
#pragma unroll
    for (int p = 0; p < 8; ++p) {
        int c4 = p * 256 + t;
        int e = c4 * 4;
        int row = e >> 7, col = e & 127;
        f32x4 v = *reinterpret_cast<const f32x4*>(src + row * IN_DIM + col);
        tile[row][col+0] = v.x; tile[row][col+1] = v.y;
        tile[row][col+2] = v.z; tile[row][col+3] = v.w;
    }
    __syncthreads();
    unsigned short* dst = W1T + (size_t)kt * (IN_DIM * 64);
#pragma unroll
    for (int it = 0; it < 4; ++it) {
        int c = it * 256 + t;
        int n = c >> 3, kl0 = (c & 7) * 8;
        uint4 w;
        w.x = f2bf(tile[kl0+0][n]) | (f2bf(tile[kl0+1][n]) << 16);
        w.y = f2bf(tile[kl0+2][n]) | (f2bf(tile[kl0+3][n]) << 16);
        w.z = f2bf(tile[kl0+4][n]) | (f2bf(tile[kl0+5][n]) << 16);
        w.w = f2bf(tile[kl0+6][n]) | (f2bf(tile[kl0+7][n]) << 16);
        *reinterpret_cast<uint4*>(dst + c * 8) = w;
    }
}

// ---------------------------------------------------------------------------
// Kernel 1: split-K GEMM partials. M = W2(8256x16512) * W1T.
// Grid 774 = 129 m-blocks x 6 k-splits, 256 thr (4 waves, 2m x 2n).
// XCD-aware mapping: blocks on one XCD share (almost) one k-split so the
// 688KB B-slice stays L2-resident. 3 blocks/CU overlap barrier drains.
// ---------------------------------------------------------------------------
__global__ __launch_bounds__(256) void k_gemm_M(const float* __restrict__ W2,
                                                const unsigned short* __restrict__ W1T,
                                                float* __restrict__ Mpart) {
    __shared__ unsigned short Ash[BM][72];    // 9.2 KB (pad: stride 144B)
    __shared__ unsigned short Bsh[128][72];   // 18.4 KB
    const int t = threadIdx.x;

    // bijective blockIdx -> (ks, mb), grouping each XCD onto <=2 k-splits.
    // 774 = 8*96 + 6: xcd 0..5 carry 97 blocks, xcd 6..7 carry 96.
    const int b = blockIdx.x;
    const int xcd = b & 7, slot = b >> 3;
    const int p = (xcd < 6) ? (xcd * 97 + slot) : (582 + (xcd - 6) * 96 + slot);
    const int ks = p / NMB;
    const int mb = p % NMB;

    const int m0 = mb * BM;
    const int g0 = ks * NT_PER;               // first k-tile of this split
    const int lane = t & 63, wid = t >> 6;
    const int wm = wid >> 1, wn = wid & 1;    // wave grid 2m x 2n
    const int l15 = lane & 15, l4 = lane >> 4;

    // A staging: thread t -> row t>>2, float cols (t&3)*4 + 16p (p=0..3)
    const int ar = t >> 2;
    const int ac = (t & 3) * 4;
    const float* abase = W2 + (size_t)(m0 + ar) * K2 + g0 * 64 + ac;
    // B staging: thread t -> 32 contiguous bf16 at t*32 of the 8192-elem tile
    const unsigned short* bbase = W1T + (size_t)g0 * 8192 + t * 32;

    f32x4 sa[4];
    uint4 sb[4];
#pragma unroll
    for (int q = 0; q < 4; ++q) sa[q] = *reinterpret_cast<const f32x4*>(abase + q * 16);
#pragma unroll
    for (int q = 0; q < 4; ++q) sb[q] = *reinterpret_cast<const uint4*>(bbase + q * 8);

    f32x4 acc[2][4];
#pragma unroll
    for (int mf = 0; mf < 2; ++mf)
#pragma unroll
        for (int nf = 0; nf < 4; ++nf)
            acc[mf][nf] = (f32x4){0.f, 0.f, 0.f, 0.f};

    for (int kt = 0; kt < NT_PER; ++kt) {
        if (kt) __syncthreads();
        // staged regs -> LDS (A: f32 -> bf16)
#pragma unroll
        for (int q = 0; q < 4; ++q) {
            uint2 w;
            w.x = f2bf(sa[q].x) | (f2bf(sa[q].y) << 16);
            w.y = f2bf(sa[q].z) | (f2bf(sa[q].w) << 16);
            *reinterpret_cast<uint2*>(&Ash[ar][ac + q * 16]) = w;
        }
#pragma unroll
        for (int q = 0; q < 4; ++q)
            *reinterpret_cast<uint4*>(&Bsh[t >> 1][(t & 1) * 32 + q * 8]) = sb[q];
        __syncthreads();
        // prefetch next tile (hides HBM latency under MFMA phase)
        if (kt + 1 < NT_PER) {
            const float* ap = abase + (kt + 1) * 64;
#pragma unroll
            for (int q = 0; q < 4; ++q) sa[q] = *reinterpret_cast<const f32x4*>(ap + q * 16);
            const unsigned short* bp = bbase + (size_t)(kt + 1) * 8192;
#pragma unroll
            for (int q = 0; q < 4; ++q) sb[q] = *reinterpret_cast<const uint4*>(bp + q * 8);
        }
        // compute: 16 MFMA per wave per K-tile
#pragma unroll
        for (int kk = 0; kk < 2; ++kk) {
#pragma unroll
            for (int mf = 0; mf < 2; ++mf) {
                bf16x8 af = *reinterpret_cast<const bf16x8*>(
                    &Ash[wm * 32 + mf * 16 + l15][kk * 32 + l4 * 8]);
#pragma unroll
                for (int nf = 0; nf < 4; ++nf) {
                    bf16x8 bfr = *reinterpret_cast<const bf16x8*>(
                        &Bsh[wn * 64 + nf * 16 + l15][kk * 32 + l4 * 8]);
                    acc[mf][nf] = __builtin_amdgcn_mfma_f32_16x16x32_bf16(af, bfr, acc[mf][nf], 0, 0, 0);
                }
            }
        }
    }
    // epilogue: C/D layout col=lane&15, row=(lane>>4)*4+r
    float* outp = Mpart + (size_t)ks * ((size_t)NFW * IN_DIM);
    const int r0 = m0 + wm * 32;
#pragma unroll
    for (int mf = 0; mf < 2; ++mf)
#pragma unroll
        for (int nf = 0; nf < 4; ++nf)
#pragma unroll
            for (int r = 0; r < 4; ++r)
                outp[(size_t)(r0 + mf * 16 + l4 * 4 + r) * IN_DIM + wn * 64 + nf * 16 + l15] =
                    acc[mf][nf][r];
}

// ---------------------------------------------------------------------------
// Kernel 1b: reduce 6 partials -> M bf16. 264,192 f32x4 chunks.
// ---------------------------------------------------------------------------
__global__ __launch_bounds__(256) void k_reduce_M(const float* __restrict__ Mpart,
                                                  unsigned short* __restrict__ Mb) {
    const int idx = blockIdx.x * 256 + threadIdx.x;
    f32x4 s = (f32x4){0.f, 0.f, 0.f, 0.f};
#pragma unroll
    for (int ks = 0; ks < KSPLIT; ++ks) {
        f32x4 v = *reinterpret_cast<const f32x4*>(
            Mpart + (size_t)ks * ((size_t)NFW * IN_DIM) + (size_t)idx * 4);
        s.x += v.x; s.y += v.y; s.z += v.z; s.w += v.w;
    }
    uint2 o;
    o.x = f2bf(s.x) | (f2bf(s.y) << 16);
    o.y = f2bf(s.z) | (f2bf(s.w) << 16);
    *reinterpret_cast<uint2*>(Mb + (size_t)idx * 4) = o;
}

// ---------------------------------------------------------------------------
// Kernel 2: U[i][j] = sum_d xs[i][d] * M[j][d].  MFMA, K=128.
// ---------------------------------------------------------------------------
__global__ __launch_bounds__(256) void k_gemm_U(const float* __restrict__ xs,
                                                const unsigned short* __restrict__ Mb,
                                                float* __restrict__ U) {
    const int t = threadIdx.x, lane = t & 63, wid = t >> 6;
    const int l15 = lane & 15, l4 = lane >> 4;
    const int bj = blockIdx.x % 129, bi = blockIdx.x / 129;
    const int i0 = bi * 64 + wid * 16;
    const int j0 = bj * 64;
    f32x4 acc[4];
#pragma unroll
    for (int nf = 0; nf < 4; ++nf) acc[nf] = (f32x4){0.f, 0.f, 0.f, 0.f};
#pragma unroll
    for (int kk = 0; kk < 4; ++kk) {
        const float* xp = xs + (size_t)(i0 + l15) * IN_DIM + kk * 32 + l4 * 8;
        f32x4 x0 = *reinterpret_cast<const f32x4*>(xp);
        f32x4 x1 = *reinterpret_cast<const f32x4*>(xp + 4);
        union { bf16x8 v; unsigned short s[8]; } af;
        af.s[0] = f2bf(x0.x); af.s[1] = f2bf(x0.y);
        af.s[2] = f2bf(x0.z); af.s[3] = f2bf(x0.w);
        af.s[4] = f2bf(x1.x); af.s[5] = f2bf(x1.y);
        af.s[6] = f2bf(x1.z); af.s[7] = f2bf(x1.w);
#pragma unroll
        for (int nf = 0; nf < 4; ++nf) {
            const unsigned short* mp = Mb + (size_t)(j0 + nf * 16 + l15) * IN_DIM + kk * 32 + l4 * 8;
            bf16x8 bfr = *reinterpret_cast<const bf16x8*>(mp);
            acc[nf] = __builtin_amdgcn_mfma_f32_16x16x32_bf16(af.v, bfr, acc[nf], 0, 0, 0);
        }
    }
    const int iw = i0 + l4 * 4;
#pragma unroll
    for (int nf = 0; nf < 4; ++nf) {
        const int j = j0 + nf * 16 + l15;
#pragma unroll
        for (int r = 0; r < 4; ++r)
            U[(size_t)(iw + r) * NFW + j] = acc[nf][r];
    }
}

// ---------------------------------------------------------------------------
// Kernel 3: 8256 sigmoid chains. 129 blocks x 64 thr (129 CUs, was 33),
// double-buffered batch-16 prefetch so HBM/L3 latency hides under compute.
// ---------------------------------------------------------------------------
__global__ __launch_bounds__(64) void k_chains(const float* __restrict__ U,
                                               const float* __restrict__ fw0,
                                               float* __restrict__ FW) {
    const int j = blockIdx.x * 64 + threadIdx.x;   // 129*64 = 8256 exact
    float fw = fw0[j];
    const float* up = U + j;
    float* fp = FW + j;
    float ucur[16], unxt[16];
#pragma unroll
    for (int q = 0; q < 16; ++q) ucur[q] = up[(size_t)q * NFW];
    for (int ib = 0; ib < BATCH; ib += 16) {
        if (ib + 16 < BATCH) {
#pragma unroll
            for (int q = 0; q < 16; ++q) unxt[q] = up[(size_t)(ib + 16 + q) * NFW];
        }
#pragma unroll
        for (int q = 0; q < 16; ++q) {
            float z = 10.0f * (fw + ucur[q] - 0.5f);
            fw = 1.0f / (1.0f + __expf(-z));
            fp[(size_t)(ib + q) * NFW] = fw;
        }
#pragma unroll
        for (int q = 0; q < 16; ++q) ucur[q] = unxt[q];
    }
}

// ---------------------------------------------------------------------------
// Kernel 4: preds. Block per i: h = relu(fw1 @ xs_i), out[i] = fw2 . h.
// ---------------------------------------------------------------------------
__global__ __launch_bounds__(256) void k_preds(const float* __restrict__ FW,
                                               const float* __restrict__ xs,
                                               float* __restrict__ out) {
    __shared__ float xsh[IN_DIM];
    __shared__ float hsh[HID];
    const int i = blockIdx.x, t = threadIdx.x;
    if (t < 32) {
        f32x4 v = *reinterpret_cast<const f32x4*>(xs + (size_t)i * IN_DIM + t * 4);
        xsh[t*4+0] = v.x; xsh[t*4+1] = v.y; xsh[t*4+2] = v.z; xsh[t*4+3] = v.w;
    }
    __syncthreads();
    const int k = t >> 2, q = t & 3;
    const float* fr = FW + (size_t)i * NFW + k * IN_DIM + q * 32;
    float p = 0.f;
#pragma unroll
    for (int m = 0; m < 8; ++m) {
        f32x4 v = *reinterpret_cast<const f32x4*>(fr + m * 4);
        const int d = q * 32 + m * 4;
        p += v.x * xsh[d] + v.y * xsh[d+1] + v.z * xsh[d+2] + v.w * xsh[d+3];
    }
    p += __shfl_xor(p, 1);
    p += __shfl_xor(p, 2);
    if (q == 0) hsh[k] = fmaxf(p, 0.f);
    __syncthreads();
    if (t < 64) {
        float v = FW[(size_t)i * NFW + IN_DIM * HID + t] * hsh[t];
        v += __shfl_xor(v, 1);  v += __shfl_xor(v, 2);  v += __shfl_xor(v, 4);
        v += __shfl_xor(v, 8);  v += __shfl_xor(v, 16); v += __shfl_xor(v, 32);
        if (t == 0) out[i] = v;
    }
}

// ---------------------------------------------------------------------------
// Workspace layout (~48.6 MiB):
//   W1T  bf16 :  4,227,072 B @ 0
//   Mpart f32 : 25,362,432 B @  4,227,072   (6 x 8256 x 128)
//   Mb   bf16 :  2,113,536 B @ 29,589,504
//   U    f32  :  8,454,144 B @ 31,703,040
//   FW   f32  :  8,454,144 B @ 40,157,184
// ---------------------------------------------------------------------------
extern "C" void kernel_launch(void* const* d_in, const int* in_sizes, int n_in,
                              void* d_out, int out_size, void* d_ws, size_t ws_size,
                              hipStream_t stream) {
    const float* x   = (const float*)d_in[0];   // (256,1,128)
    const float* W1  = (const float*)d_in[1];   // (16512,128)
    const float* W2  = (const float*)d_in[2];   // (8256,16512)
    const float* fw0 = (const float*)d_in[3];   // (8256,)
    float* out = (float*)d_out;                 // 256 f32

    char* ws = (char*)d_ws;
    unsigned short* W1T   = (unsigned short*)(ws);
    float*          Mpart = (float*)(ws + 4227072);
    unsigned short* Mb    = (unsigned short*)(ws + 29589504);
    float*          U     = (float*)(ws + 31703040);
    float*          FW    = (float*)(ws + 40157184);

    hipLaunchKernelGGL(k_prep_w1t, dim3(258),    dim3(256), 0, stream, W1, W1T);
    hipLaunchKernelGGL(k_gemm_M,   dim3(GRID_M), dim3(256), 0, stream, W2, W1T, Mpart);
    hipLaunchKernelGGL(k_reduce_M, dim3(1032),   dim3(256), 0, stream, Mpart, Mb);
    hipLaunchKernelGGL(k_gemm_U,   dim3(516),    dim3(256), 0, stream, x, Mb, U);
    hipLaunchKernelGGL(k_chains,   dim3(129),    dim3(64),  0, stream, U, fw0, FW);
    hipLaunchKernelGGL(k_preds,    dim3(256),    dim3(256), 0, stream, FW, x, out);
}

// Round 4
// 365.062 us; speedup vs baseline: 1.0667x; 1.0667x over previous
//
#include <hip/hip_runtime.h>
#include <hip/hip_bf16.h>

// Problem constants
#define IN_DIM 128
#define HID    64
#define NFW    8256     // IN*HID + HID
#define BATCH  256
#define K2     16512    // 2*NFW
#define BM     192      // rows per m-block (8256 = 43*192)
#define NMB    43
#define KSPLIT 6
#define NT_PER 43       // k-tiles (of 64) per split; 6*43 = 258
#define GRID_M 258      // NMB * KSPLIT

typedef float f32x4 __attribute__((ext_vector_type(4)));
typedef short bf16x8 __attribute__((ext_vector_type(8)));

__device__ __forceinline__ unsigned int f2bf(float f) {
    union { float f; unsigned int u; } v; v.f = f;
    return (v.u + 0x7FFFu + ((v.u >> 16) & 1u)) >> 16;   // RNE f32->bf16 (bits)
}

// ---------------------------------------------------------------------------
// Kernel 0: W1 (16512x128 f32) -> W1T tiled bf16. Tile kt: [128 n][64 kl].
// ---------------------------------------------------------------------------
__global__ __launch_bounds__(256) void k_prep_w1t(const float* __restrict__ W1,
                                                  unsigned short* __restrict__ W1T) {
    __shared__ float tile[64][IN_DIM + 1];
    const int kt = blockIdx.x;               // 0..257
    const int t  = threadIdx.x;
    const float* src = W1 + (size_t)kt * 64 * IN_DIM;
#pragma unroll
    for (int p = 0; p < 8; ++p) {
        int c4 = p * 256 + t;
        int e = c4 * 4;
        int row = e >> 7, col = e & 127;
        f32x4 v = *reinterpret_cast<const f32x4*>(src + row * IN_DIM + col);
        tile[row][col+0] = v.x; tile[row][col+1] = v.y;
        tile[row][col+2] = v.z; tile[row][col+3] = v.w;
    }
    __syncthreads();
    unsigned short* dst = W1T + (size_t)kt * (IN_DIM * 64);
#pragma unroll
    for (int it = 0; it < 4; ++it) {
        int c = it * 256 + t;
        int n = c >> 3, kl0 = (c & 7) * 8;
        uint4 w;
        w.x = f2bf(tile[kl0+0][n]) | (f2bf(tile[kl0+1][n]) << 16);
        w.y = f2bf(tile[kl0+2][n]) | (f2bf(tile[kl0+3][n]) << 16);
        w.z = f2bf(tile[kl0+4][n]) | (f2bf(tile[kl0+5][n]) << 16);
        w.w = f2bf(tile[kl0+6][n]) | (f2bf(tile[kl0+7][n]) << 16);
        *reinterpret_cast<uint4*>(dst + c * 8) = w;
    }
}

// ---------------------------------------------------------------------------
// Kernel 1: split-K GEMM, NO LDS / NO BARRIERS in the K-loop.
// A-frags: global->reg direct (f32, line-aligned, cvt to bf16 in VALU).
// B-frags: global->reg direct from L2-resident W1T slice (XCD-grouped ks).
// 4 waves x 48 rows (mf=3, nf=8); 2-stage explicit register pipeline.
// Epilogue: LDS transpose -> fully coalesced Mpart stores.
// ---------------------------------------------------------------------------
#define LOAD_A(DST, KT) do {                                                   \
    const float* _ap = abase + (size_t)(KT) * 64;                              \
    _Pragma("unroll")                                                          \
    for (int mf = 0; mf < 3; ++mf)                                             \
    { _Pragma("unroll")                                                        \
      for (int kk = 0; kk < 2; ++kk)                                           \
      { _Pragma("unroll")                                                      \
        for (int h = 0; h < 2; ++h)                                            \
          DST[mf*4 + kk*2 + h] = *reinterpret_cast<const f32x4*>(              \
              _ap + (size_t)mf * 16 * K2 + kk * 32 + h * 4); } }               \
} while (0)

#define LOAD_B(DST, KT, KK) do {                                               \
    const unsigned short* _bp = bbase + (size_t)(KT) * 8192 + (KK) * 32;       \
    _Pragma("unroll")                                                          \
    for (int nf = 0; nf < 8; ++nf)                                             \
        DST[nf] = *reinterpret_cast<const uint4*>(_bp + nf * 1024);            \
} while (0)

#define MFMA_KK(CUR, BF, KK) do {                                              \
    _Pragma("unroll")                                                          \
    for (int mf = 0; mf < 3; ++mf) {                                           \
        const f32x4 _x0 = CUR[mf*4 + (KK)*2];                                  \
        const f32x4 _x1 = CUR[mf*4 + (KK)*2 + 1];                              \
        union { bf16x8 v; unsigned short s[8]; } _u;                           \
        _u.s[0]=f2bf(_x0.x); _u.s[1]=f2bf(_x0.y);                              \
        _u.s[2]=f2bf(_x0.z); _u.s[3]=f2bf(_x0.w);                              \
        _u.s[4]=f2bf(_x1.x); _u.s[5]=f2bf(_x1.y);                              \
        _u.s[6]=f2bf(_x1.z); _u.s[7]=f2bf(_x1.w);                              \
        _Pragma("unroll")                                                      \
        for (int nf = 0; nf < 8; ++nf) {                                       \
            union { uint4 u; bf16x8 v; } _b; _b.u = BF[nf];                    \
            acc[mf][nf] = __builtin_amdgcn_mfma_f32_16x16x32_bf16(             \
                _u.v, _b.v, acc[mf][nf], 0, 0, 0);                             \
        }                                                                      \
    }                                                                          \
} while (0)

__global__ __launch_bounds__(256, 1) void k_gemm_M(const float* __restrict__ W2,
                                                   const unsigned short* __restrict__ W1T,
                                                   float* __restrict__ Mpart) {
    __shared__ float trs[48][132];            // 25.3 KB, epilogue only
    const int t = threadIdx.x;
    const int lane = t & 63, wid = t >> 6;
    const int l15 = lane & 15, l4 = (lane >> 4) & 3;

    // bijective blockIdx -> (ks, mb); blocks on one XCD share a k-split so
    // the 688KB W1T slice stays L2-resident. 258 = 2*33 + 6*32.
    const int b = blockIdx.x;
    const int xcd = b & 7, slot = b >> 3;
    const int p = (xcd < 2) ? (xcd * 33 + slot) : (66 + (xcd - 2) * 32 + slot);
    const int ks = p / NMB, mb = p % NMB;

    const int m0 = mb * BM;
    const int g0 = ks * NT_PER;

    const int row0 = m0 + wid * 48 + l15;     // this lane's A row for mf=0
    const float* abase = W2 + (size_t)row0 * K2 + (size_t)g0 * 64 + l4 * 8;
    const unsigned short* bbase = W1T + (size_t)g0 * 8192 + l15 * 64 + l4 * 8;

    f32x4 Aa[12], Ab[12];
    uint4 B0[8], B1[8];
    f32x4 acc[3][8];
#pragma unroll
    for (int mf = 0; mf < 3; ++mf)
#pragma unroll
        for (int nf = 0; nf < 8; ++nf)
            acc[mf][nf] = (f32x4){0.f, 0.f, 0.f, 0.f};

    LOAD_A(Aa, 0);
    LOAD_B(B0, 0, 0);
    LOAD_B(B1, 0, 1);

#pragma unroll 1
    for (int kt = 0; kt < NT_PER - 1; kt += 2) {
        // step kt: compute from Aa/B(kt), prefetch A(kt+1), B(kt+1)
        LOAD_A(Ab, kt + 1);
        MFMA_KK(Aa, B0, 0);
        LOAD_B(B0, kt + 1, 0);
        MFMA_KK(Aa, B1, 1);
        LOAD_B(B1, kt + 1, 1);
        // step kt+1: compute from Ab/B(kt+1), prefetch A(kt+2), B(kt+2)
        LOAD_A(Aa, kt + 2);
        MFMA_KK(Ab, B0, 0);
        LOAD_B(B0, kt + 2, 0);
        MFMA_KK(Ab, B1, 1);
        LOAD_B(B1, kt + 2, 1);
    }
    // kt = 42 (last): everything already resident
    MFMA_KK(Aa, B0, 0);
    MFMA_KK(Aa, B1, 1);

    // Epilogue: per-wave LDS transpose -> coalesced 512B global stores.
    float* outp = Mpart + (size_t)ks * ((size_t)NFW * IN_DIM) + (size_t)m0 * IN_DIM;
#pragma unroll 1
    for (int w = 0; w < 4; ++w) {
        if (wid == w) {
#pragma unroll
            for (int mf = 0; mf < 3; ++mf)
#pragma unroll
                for (int nf = 0; nf < 8; ++nf)
#pragma unroll
                    for (int r = 0; r < 4; ++r)
                        trs[mf * 16 + l4 * 4 + r][nf * 16 + l15] = acc[mf][nf][r];
        }
        __syncthreads();
#pragma unroll
        for (int q = 0; q < 6; ++q) {
            int idx = q * 256 + t;            // 0..1535 (48 rows x 32 f32x4)
            int rr = idx >> 5, c4 = (idx & 31) * 4;
            f32x4 v = *reinterpret_cast<const f32x4*>(&trs[rr][c4]);
            *reinterpret_cast<f32x4*>(outp + (size_t)(w * 48 + rr) * IN_DIM + c4) = v;
        }
        __syncthreads();
    }
}

// ---------------------------------------------------------------------------
// Kernel 1b: reduce 6 partials -> M bf16. 264,192 f32x4 chunks.
// ---------------------------------------------------------------------------
__global__ __launch_bounds__(256) void k_reduce_M(const float* __restrict__ Mpart,
                                                  unsigned short* __restrict__ Mb) {
    const int idx = blockIdx.x * 256 + threadIdx.x;
    f32x4 s = (f32x4){0.f, 0.f, 0.f, 0.f};
#pragma unroll
    for (int ks = 0; ks < KSPLIT; ++ks) {
        f32x4 v = *reinterpret_cast<const f32x4*>(
            Mpart + (size_t)ks * ((size_t)NFW * IN_DIM) + (size_t)idx * 4);
        s.x += v.x; s.y += v.y; s.z += v.z; s.w += v.w;
    }
    uint2 o;
    o.x = f2bf(s.x) | (f2bf(s.y) << 16);
    o.y = f2bf(s.z) | (f2bf(s.w) << 16);
    *reinterpret_cast<uint2*>(Mb + (size_t)idx * 4) = o;
}

// ---------------------------------------------------------------------------
// Kernel 2: U[i][j] = sum_d xs[i][d] * M[j][d].  MFMA, K=128.
// ---------------------------------------------------------------------------
__global__ __launch_bounds__(256) void k_gemm_U(const float* __restrict__ xs,
                                                const unsigned short* __restrict__ Mb,
                                                float* __restrict__ U) {
    const int t = threadIdx.x, lane = t & 63, wid = t >> 6;
    const int l15 = lane & 15, l4 = lane >> 4;
    const int bj = blockIdx.x % 129, bi = blockIdx.x / 129;
    const int i0 = bi * 64 + wid * 16;
    const int j0 = bj * 64;
    f32x4 acc[4];
#pragma unroll
    for (int nf = 0; nf < 4; ++nf) acc[nf] = (f32x4){0.f, 0.f, 0.f, 0.f};
#pragma unroll
    for (int kk = 0; kk < 4; ++kk) {
        const float* xp = xs + (size_t)(i0 + l15) * IN_DIM + kk * 32 + l4 * 8;
        f32x4 x0 = *reinterpret_cast<const f32x4*>(xp);
        f32x4 x1 = *reinterpret_cast<const f32x4*>(xp + 4);
        union { bf16x8 v; unsigned short s[8]; } af;
        af.s[0] = f2bf(x0.x); af.s[1] = f2bf(x0.y);
        af.s[2] = f2bf(x0.z); af.s[3] = f2bf(x0.w);
        af.s[4] = f2bf(x1.x); af.s[5] = f2bf(x1.y);
        af.s[6] = f2bf(x1.z); af.s[7] = f2bf(x1.w);
#pragma unroll
        for (int nf = 0; nf < 4; ++nf) {
            const unsigned short* mp = Mb + (size_t)(j0 + nf * 16 + l15) * IN_DIM + kk * 32 + l4 * 8;
            bf16x8 bfr = *reinterpret_cast<const bf16x8*>(mp);
            acc[nf] = __builtin_amdgcn_mfma_f32_16x16x32_bf16(af.v, bfr, acc[nf], 0, 0, 0);
        }
    }
    const int iw = i0 + l4 * 4;
#pragma unroll
    for (int nf = 0; nf < 4; ++nf) {
        const int j = j0 + nf * 16 + l15;
#pragma unroll
        for (int r = 0; r < 4; ++r)
            U[(size_t)(iw + r) * NFW + j] = acc[nf][r];
    }
}

// ---------------------------------------------------------------------------
// Kernel 3: 8256 sigmoid chains, double-buffered batch-16 prefetch.
// ---------------------------------------------------------------------------
__global__ __launch_bounds__(64) void k_chains(const float* __restrict__ U,
                                               const float* __restrict__ fw0,
                                               float* __restrict__ FW) {
    const int j = blockIdx.x * 64 + threadIdx.x;   // 129*64 = 8256 exact
    float fw = fw0[j];
    const float* up = U + j;
    float* fp = FW + j;
    float ucur[16], unxt[16];
#pragma unroll
    for (int q = 0; q < 16; ++q) ucur[q] = up[(size_t)q * NFW];
    for (int ib = 0; ib < BATCH; ib += 16) {
        if (ib + 16 < BATCH) {
#pragma unroll
            for (int q = 0; q < 16; ++q) unxt[q] = up[(size_t)(ib + 16 + q) * NFW];
        }
#pragma unroll
        for (int q = 0; q < 16; ++q) {
            float z = 10.0f * (fw + ucur[q] - 0.5f);
            fw = 1.0f / (1.0f + __expf(-z));
            fp[(size_t)(ib + q) * NFW] = fw;
        }
#pragma unroll
        for (int q = 0; q < 16; ++q) ucur[q] = unxt[q];
    }
}

// ---------------------------------------------------------------------------
// Kernel 4: preds. Block per i: h = relu(fw1 @ xs_i), out[i] = fw2 . h.
// ---------------------------------------------------------------------------
__global__ __launch_bounds__(256) void k_preds(const float* __restrict__ FW,
                                               const float* __restrict__ xs,
                                               float* __restrict__ out) {
    __shared__ float xsh[IN_DIM];
    __shared__ float hsh[HID];
    const int i = blockIdx.x, t = threadIdx.x;
    if (t < 32) {
        f32x4 v = *reinterpret_cast<const f32x4*>(xs + (size_t)i * IN_DIM + t * 4);
        xsh[t*4+0] = v.x; xsh[t*4+1] = v.y; xsh[t*4+2] = v.z; xsh[t*4+3] = v.w;
    }
    __syncthreads();
    const int k = t >> 2, q = t & 3;
    const float* fr = FW + (size_t)i * NFW + k * IN_DIM + q * 32;
    float p = 0.f;
#pragma unroll
    for (int m = 0; m < 8; ++m) {
        f32x4 v = *reinterpret_cast<const f32x4*>(fr + m * 4);
        const int d = q * 32 + m * 4;
        p += v.x * xsh[d] + v.y * xsh[d+1] + v.z * xsh[d+2] + v.w * xsh[d+3];
    }
    p += __shfl_xor(p, 1);
    p += __shfl_xor(p, 2);
    if (q == 0) hsh[k] = fmaxf(p, 0.f);
    __syncthreads();
    if (t < 64) {
        float v = FW[(size_t)i * NFW + IN_DIM * HID + t] * hsh[t];
        v += __shfl_xor(v, 1);  v += __shfl_xor(v, 2);  v += __shfl_xor(v, 4);
        v += __shfl_xor(v, 8);  v += __shfl_xor(v, 16); v += __shfl_xor(v, 32);
        if (t == 0) out[i] = v;
    }
}

// ---------------------------------------------------------------------------
// Workspace layout (~48.6 MiB):
//   W1T  bf16 :  4,227,072 B @ 0
//   Mpart f32 : 25,362,432 B @  4,227,072   (6 x 8256 x 128)
//   Mb   bf16 :  2,113,536 B @ 29,589,504
//   U    f32  :  8,454,144 B @ 31,703,040
//   FW   f32  :  8,454,144 B @ 40,157,184
// ---------------------------------------------------------------------------
extern "C" void kernel_launch(void* const* d_in, const int* in_sizes, int n_in,
                              void* d_out, int out_size, void* d_ws, size_t ws_size,
                              hipStream_t stream) {
    const float* x   = (const float*)d_in[0];   // (256,1,128)
    const float* W1  = (const float*)d_in[1];   // (16512,128)
    const float* W2  = (const float*)d_in[2];   // (8256,16512)
    const float* fw0 = (const float*)d_in[3];   // (8256,)
    float* out = (float*)d_out;                 // 256 f32

    char* ws = (char*)d_ws;
    unsigned short* W1T   = (unsigned short*)(ws);
    float*          Mpart = (float*)(ws + 4227072);
    unsigned short* Mb    = (unsigned short*)(ws + 29589504);
    float*          U     = (float*)(ws + 31703040);
    float*          FW    = (float*)(ws + 40157184);

    hipLaunchKernelGGL(k_prep_w1t, dim3(258),    dim3(256), 0, stream, W1, W1T);
    hipLaunchKernelGGL(k_gemm_M,   dim3(GRID_M), dim3(256), 0, stream, W2, W1T, Mpart);
    hipLaunchKernelGGL(k_reduce_M, dim3(1032),   dim3(256), 0, stream, Mpart, Mb);
    hipLaunchKernelGGL(k_gemm_U,   dim3(516),    dim3(256), 0, stream, x, Mb, U);
    hipLaunchKernelGGL(k_chains,   dim3(129),    dim3(64),  0, stream, U, fw0, FW);
    hipLaunchKernelGGL(k_preds,    dim3(256),    dim3(256), 0, stream, FW, x, out);
}